// Round 2
// baseline (740.777 us; speedup 1.0000x reference)
//
#include <hip/hip_runtime.h>
#include <stdint.h>

// ClassicalHopfield N=8192, P=64.
// act_i = (x_i·m - 64*s_i)/N, m = X^T s (running). Blocked (64-neuron) serial
// resolve; cross-neuron corrections via sign signatures:
//   y = s⊙x ∈ {±1}^64,  y_i·y_j = 64 - 2*pc(sig_i^sig_j),
//   flip i ⇒ q_j += 4*pc(sig_i^sig_j) - 128.
// q_j = y_j·m - 64 (-0.5 extra if s_j<0 for the exact act>=0→+1 tie-break).
// Everything is a small integer (±0.5) => exact in f32 => bit-identical to ref.

#define NN 8192
#define NB 128
typedef unsigned long long u64;

// ws (floats): m_part[8192] | Ysw[128*4096] | sig[8192 u64] | sp[8192]  ≈ 2.2 MB

__device__ __forceinline__ void glds16(const void* g, void* l) {
  __builtin_amdgcn_global_load_lds(
      (const __attribute__((address_space(1))) void*)g,
      (__attribute__((address_space(3))) void*)l, 16, 0, 0);
}

__global__ __launch_bounds__(256) void hop_prep(
    const float* __restrict__ X, const float* __restrict__ state,
    const int* __restrict__ perm, float* __restrict__ m_part,
    float* __restrict__ Ysw, u64* __restrict__ sig, float* __restrict__ sp)
{
  const int b = blockIdx.x;
  const int t = threadIdx.x;

  // ---- A: sign-scaled Y rows, XOR-swizzled at float4 granularity
  // Yphys[j][G ^ (j&7)] = Ylog[j][G]  (G = float4 index 0..15)
  {
    const int j = t >> 2, qc = t & 3;
    const int r = perm[b*64 + j];
    const float s = state[r];
    const float4* xr = (const float4*)(X + (size_t)r*64) + qc*4;
    float4* yw = (float4*)(Ysw + (size_t)b*4096 + j*64);
    #pragma unroll
    for (int kk = 0; kk < 4; ++kk) {
      float4 x = xr[kk];
      float4 y; y.x = x.x*s; y.y = x.y*s; y.z = x.z*s; y.w = x.w*s;
      yw[(qc*4 + kk) ^ (j & 7)] = y;
    }
  }

  // ---- B: 64-bit sign signatures, one ballot per row
  {
    const int wv = t >> 6, ln = t & 63;
    #pragma unroll
    for (int jj = 0; jj < 16; ++jj) {
      const int j = wv*16 + jj;
      const int r = perm[b*64 + j];
      u64 bb = __ballot(X[(size_t)r*64 + ln] < 0.f);
      if (state[r] < 0.f) bb = ~bb;
      if (ln == 0) sig[b*64 + j] = bb;
    }
  }

  // ---- C: per-block m partials (order-free exact integer sums); D: sp
  {
    __shared__ float red[4][64];
    const int p = t & 63, g = t >> 6;
    float acc = 0.f;
    for (int jj = 0; jj < 16; ++jj) {
      const int r = perm[b*64 + g*16 + jj];
      acc = fmaf(X[(size_t)r*64 + p], state[r], acc);
    }
    red[g][p] = acc;
    __syncthreads();
    if (t < 64) {
      m_part[b*64 + t] = (red[0][t] + red[1][t]) + (red[2][t] + red[3][t]);
      sp[b*64 + t] = state[perm[b*64 + t]];
    }
  }
}

__global__ __launch_bounds__(64) void hop_solve(
    const int* __restrict__ perm, const float* __restrict__ m_part,
    const float* __restrict__ Ysw, const u64* __restrict__ sig,
    const float* __restrict__ sp, float* __restrict__ out)
{
  __shared__ __align__(16) float mlds[64];
  __shared__ __align__(16) float Ybuf[2][4096];
  const int lane = threadIdx.x;   // one wave

  { // m = sum of per-block partials (exact)
    float a = 0.f;
    for (int k = 0; k < NB; ++k) a += m_part[k*64 + lane];
    mlds[lane] = a;
  }
  { // stage block 0
    const float* ys = Ysw + lane*4;
    #pragma unroll
    for (int it = 0; it < 16; ++it) glds16(ys + it*256, &Ybuf[0][it*256]);
  }
  int   r_cur = perm[lane];
  float s_cur = sp[lane];
  u64   g_cur = sig[lane];
  asm volatile("s_waitcnt vmcnt(0)" ::: "memory");

  int cur = 0;
  for (int b = 0; b < NB; ++b) {
    int r_next = 0; float s_next = 0.f; u64 g_next = 0ull;
    if (b + 1 < NB) {  // prefetch next block (Y -> LDS, scalars -> regs)
      const float* ys = Ysw + (size_t)(b+1)*4096 + lane*4;
      #pragma unroll
      for (int it = 0; it < 16; ++it) glds16(ys + it*256, &Ybuf[cur^1][it*256]);
      r_next = perm[(b+1)*64 + lane];
      s_next = sp[(b+1)*64 + lane];
      g_next = sig[(b+1)*64 + lane];
    }

    // q_lane = y_lane · m  (swizzled b128 reads: 8/bank minimum; m broadcast)
    float q0=0.f,q1=0.f,q2=0.f,q3=0.f;
    #pragma unroll
    for (int g = 0; g < 16; ++g) {
      const float4 yv = *(const float4*)&Ybuf[cur][lane*64 + ((g ^ (lane & 7)) << 2)];
      const float4 mv = *(const float4*)&mlds[g*4];
      q0 = fmaf(yv.x, mv.x, q0); q1 = fmaf(yv.y, mv.y, q1);
      q2 = fmaf(yv.z, mv.z, q2); q3 = fmaf(yv.w, mv.w, q3);
    }
    float q = ((q0+q1)+(q2+q3)) + (s_cur < 0.f ? -64.5f : -64.0f);

    // skip-ahead sequential resolve: one iteration per FLIP
    u64 flips = 0ull, live = ~0ull;
    const u64 myb = g_cur;
    while (true) {
      const u64 mm = __ballot(q < 0.f) & live;
      if (!mm) break;
      const int i = (int)__builtin_ctzll(mm);
      flips |= (mm & (~mm + 1ull));
      live = (i < 63) ? ((~0ull) << (i + 1)) : 0ull;
      const unsigned blo = (unsigned)__builtin_amdgcn_readlane((int)(unsigned)myb, i);
      const unsigned bhi = (unsigned)__builtin_amdgcn_readlane((int)(myb >> 32), i);
      const u64 xb = myb ^ (((u64)bhi << 32) | (u64)blo);
      q += fmaf(4.0f, (float)__popcll(xb), -128.0f);   // Λ correction, exact
    }

    if (flips) {  // m -= 2 * Σ_flips y_i  (column reads, conflict-free)
      float dm = 0.f;
      u64 f = flips;
      do {
        const int i = (int)__builtin_ctzll(f); f &= f - 1ull;
        dm += Ybuf[cur][i*64 + ((((lane >> 2) ^ (i & 7)) << 2) | (lane & 3))];
      } while (f);
      mlds[lane] -= 2.0f * dm;
    }

    out[r_cur] = ((flips >> lane) & 1ull) ? -s_cur : s_cur;

    asm volatile("s_waitcnt vmcnt(0)" ::: "memory");  // next block resident
    r_cur = r_next; s_cur = s_next; g_cur = g_next; cur ^= 1;
  }
}

extern "C" void kernel_launch(void* const* d_in, const int* in_sizes, int n_in,
                              void* d_out, int out_size, void* d_ws, size_t ws_size,
                              hipStream_t stream) {
  const float* X     = (const float*)d_in[0];
  const float* state = (const float*)d_in[1];
  const int*   perm  = (const int*)d_in[2];
  float* outp   = (float*)d_out;
  float* m_part = (float*)d_ws;                       // 8192 f
  float* Ysw    = m_part + 8192;                      // 524288 f
  u64*   sig    = (u64*)(Ysw + 524288);               // 8192 u64
  float* sp     = (float*)(sig + 8192);               // 8192 f

  hop_prep<<<dim3(NB), dim3(256), 0, stream>>>(X, state, perm, m_part, Ysw, sig, sp);
  hop_solve<<<dim3(1), dim3(64), 0, stream>>>(perm, m_part, Ysw, sig, sp, outp);
}

// Round 3
// 453.188 us; speedup vs baseline: 1.6346x; 1.6346x over previous
//
#include <hip/hip_runtime.h>
#include <stdint.h>

// ClassicalHopfield N=8192, P=64.  act_i·N = x_i·m - 64·s_i, m = X^T s (running).
// Blocked (64-neuron) sequential resolve, all corrections via 64-bit sign
// signatures (y = s⊙x ∈ {±1}^64):
//   flip i:   q_j += 4·popc(sig_i ^ sig_j) - 128          (= -2·y_i·y_j)
//   block end: m_p += 4·popc(flips & sigT_p) - 2·nf        (= -2·Σ_flips y_i[p])
// q_j = y_j·m - 64 (-64.5 if s_j<0: exact act>=0→+1 tie-break). All quantities
// are small integers/half-integers => exact in f32 => bit-identical to ref.

#define NB 128
typedef unsigned long long u64;

// ws layout: m0 f[64] | Yt f[128*4096] (transposed: [b][G][j][c]) |
//            sig u64[8192] | sigT u64[8192] | sps f[8192]   ≈ 2.16 MB

__global__ __launch_bounds__(256) void hop_prep(
    const float* __restrict__ X, const float* __restrict__ state,
    const int* __restrict__ perm, float* __restrict__ m0,
    float* __restrict__ Yt, u64* __restrict__ sig, u64* __restrict__ sigT,
    float* __restrict__ sps)
{
  const int b = blockIdx.x;
  const int t = threadIdx.x;
  const int wv = t >> 6, ln = t & 63;
  __shared__ u64 sigL[64];
  __shared__ float red[4][64];

  // ---- A: sign-scaled Y rows, transposed layout Yt4[b*1024 + G*64 + j]
  {
    const int j = t >> 2, qc = t & 3;
    const int r = perm[b*64 + j];
    const float s = state[r];
    const float4* xr = (const float4*)(X + (size_t)r*64) + qc*4;
    float4* yw = (float4*)Yt + (size_t)b*1024 + j;
    #pragma unroll
    for (int kk = 0; kk < 4; ++kk) {
      float4 x = xr[kk];
      float4 y; y.x = x.x*s; y.y = x.y*s; y.z = x.z*s; y.w = x.w*s;
      yw[(qc*4 + kk) * 64] = y;
    }
  }

  // ---- B: row signatures (bit p of sig_j = (y_j[p] < 0)), one ballot/row
  #pragma unroll
  for (int jj = 0; jj < 16; ++jj) {
    const int j = wv*16 + jj;
    const int r = perm[b*64 + j];
    u64 bb = __ballot(X[(size_t)r*64 + ln] < 0.f);
    if (state[r] < 0.f) bb = ~bb;
    if (ln == 0) { sig[b*64 + j] = bb; sigL[j] = bb; }
  }
  __syncthreads();

  // ---- B': column signatures (bit i of sigT_p = bit p of sig_i)
  {
    const u64 gs = sigL[ln];
    #pragma unroll
    for (int jj = 0; jj < 16; ++jj) {
      const int p = wv*16 + jj;
      u64 tb = __ballot((unsigned)((gs >> p) & 1ull));
      if (ln == 0) sigT[b*64 + p] = tb;
    }
  }

  // ---- C: m0 += per-block partial (exact small ints; atomic order-free)
  {
    float acc = 0.f;
    for (int jj = 0; jj < 16; ++jj) {
      const int r = perm[b*64 + wv*16 + jj];
      acc = fmaf(X[(size_t)r*64 + ln], state[r], acc);
    }
    red[wv][ln] = acc;
    __syncthreads();
    if (t < 64) {
      atomicAdd(&m0[t], (red[0][t] + red[1][t]) + (red[2][t] + red[3][t]));
      sps[b*64 + t] = state[perm[b*64 + t]];   // ---- D
    }
  }
}

// Process one 64-neuron block. All loops fully unrolled; Y indices static.
#define PROCESS(Y, gsig, gsigT, rr, ss) {                                     \
  float q0=0.f,q1=0.f,q2=0.f,q3=0.f;                                          \
  const float4* mv4 = (const float4*)mlds;                                    \
  _Pragma("unroll")                                                           \
  for (int g = 0; g < 16; ++g) {                                              \
    const float4 yv = Y[g]; const float4 mv = mv4[g];                         \
    q0 = fmaf(yv.x, mv.x, q0); q1 = fmaf(yv.y, mv.y, q1);                     \
    q2 = fmaf(yv.z, mv.z, q2); q3 = fmaf(yv.w, mv.w, q3);                     \
  }                                                                           \
  float q = ((q0+q1)+(q2+q3)) + ((ss < 0.f) ? -64.5f : -64.0f);               \
  u64 flips = 0ull, live = ~0ull;                                             \
  for (;;) {                                                                  \
    const u64 mm = __ballot(q < 0.f) & live;                                  \
    if (!mm) break;                                                           \
    const int i = (int)__builtin_ctzll(mm);                                   \
    flips |= (mm & (~mm + 1ull));                                             \
    live = (i < 63) ? ((~0ull) << (i + 1)) : 0ull;                            \
    const unsigned blo = (unsigned)__builtin_amdgcn_readlane((int)(unsigned)(gsig), i); \
    const unsigned bhi = (unsigned)__builtin_amdgcn_readlane((int)((gsig) >> 32), i);   \
    const u64 xb = (gsig) ^ (((u64)bhi << 32) | (u64)blo);                    \
    q = fmaf(4.0f, (float)__popcll(xb), q - 128.0f);                          \
  }                                                                           \
  if (flips) {                                                                \
    const int nf = (int)__popcll(flips);                                      \
    const int pc = (int)__popcll(flips & (gsigT));                            \
    mreg += (float)(4*pc - 2*nf);                                             \
    mlds[lane] = mreg;                                                        \
  }                                                                           \
  out[rr] = ((flips >> lane) & 1ull) ? -(ss) : (ss);                          \
}

__global__ __launch_bounds__(64) void hop_solve(
    const int* __restrict__ perm, const float* __restrict__ m0,
    const float4* __restrict__ Yt4, const u64* __restrict__ sig,
    const u64* __restrict__ sigT, const float* __restrict__ sps,
    float* __restrict__ out)
{
  __shared__ __align__(16) float mlds[64];
  const int lane = threadIdx.x;          // one wave; lane = row j AND pattern p

  float mreg = m0[lane];
  mlds[lane] = mreg;

  float4 Ya[16], Yb[16];
  u64 sgA, stA, sgB, stB; int rA, rB; float sA, sB;

  { // prefetch block 0 -> A
    const float4* yp = Yt4 + lane;
    #pragma unroll
    for (int g = 0; g < 16; ++g) Ya[g] = yp[g*64];
    sgA = sig[lane]; stA = sigT[lane]; rA = perm[lane]; sA = sps[lane];
  }

  for (int bb = 0; bb < NB; bb += 2) {
    { // prefetch bb+1 -> B  (bb+1 <= 127, always valid)
      const int bn = bb + 1;
      const float4* yp = Yt4 + (size_t)bn*1024 + lane;
      #pragma unroll
      for (int g = 0; g < 16; ++g) Yb[g] = yp[g*64];
      sgB = sig[bn*64+lane]; stB = sigT[bn*64+lane];
      rB = perm[bn*64+lane]; sB = sps[bn*64+lane];
    }
    PROCESS(Ya, sgA, stA, rA, sA);
    { // prefetch bb+2 -> A  (clamped; last is a harmless re-read)
      const int bn = (bb + 2 < NB) ? bb + 2 : NB - 1;
      const float4* yp = Yt4 + (size_t)bn*1024 + lane;
      #pragma unroll
      for (int g = 0; g < 16; ++g) Ya[g] = yp[g*64];
      sgA = sig[bn*64+lane]; stA = sigT[bn*64+lane];
      rA = perm[bn*64+lane]; sA = sps[bn*64+lane];
    }
    PROCESS(Yb, sgB, stB, rB, sB);
  }
}

extern "C" void kernel_launch(void* const* d_in, const int* in_sizes, int n_in,
                              void* d_out, int out_size, void* d_ws, size_t ws_size,
                              hipStream_t stream) {
  const float* X     = (const float*)d_in[0];
  const float* state = (const float*)d_in[1];
  const int*   perm  = (const int*)d_in[2];
  float* outp = (float*)d_out;

  float* m0  = (float*)d_ws;                 // 64 f
  float* Yt  = m0 + 64;                      // 128*4096 f
  u64*   sig = (u64*)(Yt + 128*4096);        // 8192 u64
  u64*   sigT= sig + 8192;                   // 8192 u64
  float* sps = (float*)(sigT + 8192);        // 8192 f

  hipMemsetAsync(m0, 0, 64*sizeof(float), stream);
  hop_prep<<<dim3(NB), dim3(256), 0, stream>>>(X, state, perm, m0, Yt, sig, sigT, sps);
  hop_solve<<<dim3(1), dim3(64), 0, stream>>>(perm, m0, (const float4*)Yt, sig, sigT, sps, outp);
}

// Round 4
// 368.206 us; speedup vs baseline: 2.0119x; 1.2308x over previous
//
#include <hip/hip_runtime.h>
#include <stdint.h>

// ClassicalHopfield N=8192, P=64.  act_i·N = x_i·m - 64·s_i, m = X^T s (running).
// Blocked (64-neuron) sequential resolve; corrections via 64-bit sign
// signatures (y = s⊙x ∈ {±1}^64):
//   flip i:    Δ(y_j·m) = -2·y_j·y_i = 4·popc(sig_i^sig_j) - 128
//   block end: m_p += 4·popc(flips & sigT_p) - 2·nf
// Integer resolve domain: T_j = 2·(y_j·m) - (s_j<0), flip ⟺ T_j < thr,
// thr = 128 + 256·(#flips so far), per-flip T += 8·popc(sig_i^sig_j).
// All values are small integers => exact => bit-identical to the reference
// (the -(s<0) term implements the act==0 -> +1 tie-break exactly).

#define NB 128
typedef unsigned long long u64;
typedef unsigned u32;

// ws: m0 f[64] | Yt f[128*4096] ([b][G][j][c], G=p>>2, c=p&3) |
//     sig u64[8192] | sigT u64[8192] | sps f[8192]   ~2.16 MB

__global__ __launch_bounds__(256) void hop_prep(
    const float* __restrict__ X, const float* __restrict__ state,
    const int* __restrict__ perm, float* __restrict__ m0,
    float* __restrict__ Yt, u64* __restrict__ sig, u64* __restrict__ sigT,
    float* __restrict__ sps)
{
  const int b = blockIdx.x, t = threadIdx.x;
  const int wv = t >> 6, ln = t & 63;
  __shared__ u64 sigL[64];
  __shared__ float red[4][64];

  // single X pass: Y-store + row signature + m0 partial, per row
  float acc = 0.f;
  #pragma unroll
  for (int jj = 0; jj < 16; ++jj) {
    const int j = wv*16 + jj;                 // wave-uniform row
    const int r = perm[b*64 + j];
    const float sr = state[r];
    const float x = X[(size_t)r*64 + ln];     // coalesced 256B row
    Yt[(size_t)b*4096 + (ln >> 2)*256 + j*4 + (ln & 3)] = x * sr;
    u64 bb = __ballot(x < 0.f);
    if (sr < 0.f) bb = ~bb;                   // sign of y = x*sr
    if (ln == 0) { sig[b*64 + j] = bb; sigL[j] = bb; }
    acc = fmaf(x, sr, acc);
  }
  red[wv][ln] = acc;
  __syncthreads();

  // column signatures: bit i of sigT_p = bit p of sig_i
  {
    const u64 gs = sigL[ln];
    #pragma unroll
    for (int jj = 0; jj < 16; ++jj) {
      const int p = wv*16 + jj;
      u64 tb = __ballot((unsigned)((gs >> p) & 1ull));
      if (ln == 0) sigT[b*64 + p] = tb;
    }
  }

  if (t < 64) {
    atomicAdd(&m0[t], (red[0][t] + red[1][t]) + (red[2][t] + red[3][t]));
    sps[b*64 + t] = state[perm[b*64 + t]];
  }
}

// One 64-neuron block: register matvec -> int T -> asm skip-ahead resolve.
#define PROCESS(Y, gsig, gsigT, rr, ss) {                                     \
  float q0=0.f,q1=0.f,q2=0.f,q3=0.f;                                          \
  const float4* mv4 = (const float4*)mlds;                                    \
  _Pragma("unroll")                                                           \
  for (int g = 0; g < 16; ++g) {                                              \
    const float4 yv = Y[g]; const float4 mv = mv4[g];                         \
    q0 = fmaf(yv.x, mv.x, q0); q1 = fmaf(yv.y, mv.y, q1);                     \
    q2 = fmaf(yv.z, mv.z, q2); q3 = fmaf(yv.w, mv.w, q3);                     \
  }                                                                           \
  const float qf = (q0+q1)+(q2+q3);          /* = y·m, exact integer */       \
  int T = ((int)qf << 1) - (((ss) < 0.f) ? 1 : 0);                            \
  u64 flips;                                                                  \
  {                                                                           \
    const u32 siglo = (u32)(gsig), sighi = (u32)((gsig) >> 32);               \
    int thr = 128;                                                            \
    u64 live, mm, bit; u32 i_, t0, t1, v0, v1;                                \
    asm volatile(                                                             \
      "s_mov_b64 %[flips], 0\n\t"                                             \
      "s_mov_b64 %[live], -1\n\t"                                             \
      "1:\n\t"                                                                \
      "v_cmp_gt_i32 vcc, %[thr], %[T]\n\t"      /* T < thr ? */               \
      "s_and_b64 %[mm], vcc, %[live]\n\t"       /* sets SCC */                \
      "s_cbranch_scc0 2f\n\t"                                                 \
      "s_ff1_i32_b64 %[i], %[mm]\n\t"                                         \
      "v_readlane_b32 %[t0], %[siglo], %[i]\n\t"                              \
      "v_readlane_b32 %[t1], %[sighi], %[i]\n\t"                              \
      "s_lshl_b64 %[bit], 1, %[i]\n\t"          /* SALU shadow covers  */     \
      "s_or_b64 %[flips], %[flips], %[bit]\n\t" /* readlane->VALU SGPR */     \
      "s_lshl_b64 %[live], -2, %[i]\n\t"        /* hazard window       */     \
      "s_addk_i32 %[thr], 0x100\n\t"            /* thr += 256 */              \
      "v_xor_b32 %[v0], %[t0], %[siglo]\n\t"                                  \
      "v_xor_b32 %[v1], %[t1], %[sighi]\n\t"                                  \
      "v_bcnt_u32_b32 %[v0], %[v0], 0\n\t"                                    \
      "v_bcnt_u32_b32 %[v0], %[v1], %[v0]\n\t"                                \
      "v_lshl_add_u32 %[T], %[v0], 3, %[T]\n\t" /* T += 8*popc */             \
      "s_branch 1b\n\t"                                                       \
      "2:\n\t"                                                                \
      : [flips]"=&s"(flips), [live]"=&s"(live), [mm]"=&s"(mm),                \
        [bit]"=&s"(bit), [i]"=&s"(i_), [t0]"=&s"(t0), [t1]"=&s"(t1),          \
        [thr]"+s"(thr), [T]"+v"(T), [v0]"=&v"(v0), [v1]"=&v"(v1)              \
      : [siglo]"v"(siglo), [sighi]"v"(sighi)                                  \
      : "vcc", "scc");                                                        \
  }                                                                           \
  if (flips) {                                                                \
    const int nf = (int)__popcll(flips);                                      \
    const int pc = (int)__popcll(flips & (gsigT));                            \
    mreg += (float)(4*pc - 2*nf);                                             \
    mlds[lane] = mreg;                                                        \
  }                                                                           \
  out[rr] = ((flips >> lane) & 1ull) ? -(ss) : (ss);                          \
}

__global__ __launch_bounds__(64) void hop_solve(
    const int* __restrict__ perm, const float* __restrict__ m0,
    const float4* __restrict__ Yt4, const u64* __restrict__ sig,
    const u64* __restrict__ sigT, const float* __restrict__ sps,
    float* __restrict__ out)
{
  __shared__ __align__(16) float mlds[64];
  const int lane = threadIdx.x;          // one wave; lane = row j AND pattern p

  float mreg = m0[lane];
  mlds[lane] = mreg;

  float4 Ya[16], Yb[16];
  u64 sgA, stA, sgB, stB; int rA, rB; float sA, sB;

  { // prefetch block 0 -> A
    const float4* yp = Yt4 + lane;
    #pragma unroll
    for (int g = 0; g < 16; ++g) Ya[g] = yp[g*64];
    sgA = sig[lane]; stA = sigT[lane]; rA = perm[lane]; sA = sps[lane];
  }

  for (int bb = 0; bb < NB; bb += 2) {
    { // prefetch bb+1 -> B
      const int bn = bb + 1;
      const float4* yp = Yt4 + (size_t)bn*1024 + lane;
      #pragma unroll
      for (int g = 0; g < 16; ++g) Yb[g] = yp[g*64];
      sgB = sig[bn*64+lane]; stB = sigT[bn*64+lane];
      rB = perm[bn*64+lane]; sB = sps[bn*64+lane];
    }
    PROCESS(Ya, sgA, stA, rA, sA);
    { // prefetch bb+2 -> A (clamped; last is a harmless re-read)
      const int bn = (bb + 2 < NB) ? bb + 2 : NB - 1;
      const float4* yp = Yt4 + (size_t)bn*1024 + lane;
      #pragma unroll
      for (int g = 0; g < 16; ++g) Ya[g] = yp[g*64];
      sgA = sig[bn*64+lane]; stA = sigT[bn*64+lane];
      rA = perm[bn*64+lane]; sA = sps[bn*64+lane];
    }
    PROCESS(Yb, sgB, stB, rB, sB);
  }
}

extern "C" void kernel_launch(void* const* d_in, const int* in_sizes, int n_in,
                              void* d_out, int out_size, void* d_ws, size_t ws_size,
                              hipStream_t stream) {
  const float* X     = (const float*)d_in[0];
  const float* state = (const float*)d_in[1];
  const int*   perm  = (const int*)d_in[2];
  float* outp = (float*)d_out;

  float* m0  = (float*)d_ws;                 // 64 f
  float* Yt  = m0 + 64;                      // 128*4096 f
  u64*   sig = (u64*)(Yt + 128*4096);        // 8192 u64
  u64*   sigT= sig + 8192;                   // 8192 u64
  float* sps = (float*)(sigT + 8192);        // 8192 f

  hipMemsetAsync(m0, 0, 64*sizeof(float), stream);
  hop_prep<<<dim3(NB), dim3(256), 0, stream>>>(X, state, perm, m0, Yt, sig, sigT, sps);
  hop_solve<<<dim3(1), dim3(64), 0, stream>>>(perm, m0, (const float4*)Yt, sig, sigT, sps, outp);
}